// Round 6
// baseline (518.213 us; speedup 1.0000x reference)
//
#include <hip/hip_runtime.h>
#include <stdint.h>
#include <stddef.h>

typedef __bf16 bf16;
typedef __bf16 bf16x8 __attribute__((ext_vector_type(8)));
typedef float  f32x4  __attribute__((ext_vector_type(4)));

#define GLOBAL_AS(p) ((const __attribute__((address_space(1))) void*)(p))
#define LDS_AS(p)    ((__attribute__((address_space(3))) void*)(p))

__device__ __forceinline__ void gload_lds16(const bf16* g, bf16* l) {
    // global_load_lds_dwordx4: LDS dest = wave-uniform base + lane*16 (caller guarantees)
    __builtin_amdgcn_global_load_lds(GLOBAL_AS(g), LDS_AS(l), 16, 0, 0);
}

// ---------------------------------------------------------------------------
// x (f32) -> bf16, 8 elems/thread, both directions coalesced
// ---------------------------------------------------------------------------
__global__ __launch_bounds__(256)
void convert_x_kernel(const float* __restrict__ x, bf16* __restrict__ xb, long n8) {
    long t = (long)blockIdx.x * blockDim.x + threadIdx.x;
    if (t >= n8) return;
    const f32x4* p = (const f32x4*)(x + t * 8);
    f32x4 a = p[0], b = p[1];
    bf16x8 v;
#pragma unroll
    for (int j = 0; j < 4; ++j) { v[j] = (bf16)a[j]; v[4 + j] = (bf16)b[j]; }
    *(bf16x8*)(xb + t * 8) = v;
}

// ---------------------------------------------------------------------------
// Dequant to K-TILED layout for BK=64: Wt[K/64][N][64], Wt[t][o][cc] = W^T[o][t*64+cc]
// ---------------------------------------------------------------------------
__global__ __launch_bounds__(256)
void dequant_wt64_kernel(const uint32_t* __restrict__ qw,
                         const float* __restrict__ scales,
                         const float* __restrict__ qzeros,
                         bf16* __restrict__ Wt,
                         int N, int K, int rows_per_group) {
    const int i = blockIdx.x * 256 + threadIdx.x;
    const int w = i >> 6, l = i & 63;
    const int nr8 = K >> 6;                  // 8-row groups (64 k each)
    const int r8 = w % nr8;
    const int o  = (w / nr8) * 8 + (l >> 3);
    const int rr = l & 7;
    const int r  = r8 * 8 + rr;              // qweight row; k = r*8 + j
    if (o >= N) return;
    const uint32_t q = qw[(size_t)r * N + o];
    const int g = r / rows_per_group;
    const float s = scales[(size_t)g * N + o];
    const float z = qzeros[(size_t)g * N + o];
    const float nsz = -s * z;
    bf16x8 v;
#pragma unroll
    for (int j = 0; j < 8; ++j)
        v[j] = (bf16)fmaf((float)((q >> (4 * j)) & 15u), s, nsz);
    *(bf16x8*)(Wt + ((size_t)r8 * N + o) * 64 + rr * 8) = v;
}

// ===========================================================================
// 256x256 8-phase GEMM — SCHEDULE P2 (fragment-pipelined, overhead-stripped).
//
// R5 diagnosis: phase wall 1371 cyc vs m201's 824 at identical geometry.
// ~550 cyc/phase of excess: 2 extra barriers/iter (ph4/ph8), sched_barrier
// walls, per-call 64-bit address recompute, unbalanced reads (12 in one
// phase). P2 keeps schedule P's fragment pipeline (reads feed the NEXT
// quantum; lgkm drain after MFMA) and strips the overhead:
//   - ONE barrier per phase (8/iter). vmcnt(4) folded into ph3/ph7 ends.
//   - reads <= 8 per phase; ph7 has 0 reads so A(T+3) stages there.
//   - stage src pointers precomputed; per call = 32-bit mul + 64-bit add.
//   - 2 sched_barriers/phase: after stages (pin early issue), after barrier.
//
// Quanta (16 MFMA): Q1..Q4 = buf0 (kk0 i0-3, kk0 i4-7, kk1 i0-3, kk1 i4-7),
// Q5..Q8 same on buf1. Phase p runs quantum Qp on fragments read in p-1.
//
// Per-phase: [reads for Q(p+1)] [stages] ; SB ; prio1 ; MFMA Qp ; prio0 ;
//            lgkm(0) ; [vmcnt(4) @ph3,ph7] ; BAR ; SB
//   ph1: rd fa0H(b0,k0)+fb1(b0,k1) [8] ; stage B(T+1)->buf1 ; MFMA Q1
//   ph2: rd fa1L(b0,k1) [4]                                 ; MFMA Q2
//   ph3: rd fa1H(b0,k1) [4] ; stage B(T+2)->buf0 ; vmcnt(4) ; MFMA Q3
//   ph4: rd fa0L+fb0 (b1,k0) [8] ; stage A(T+2)->buf0       ; MFMA Q4
//   ph5: rd fa0H(b1,k0)+fb1(b1,k1) [8]                      ; MFMA Q5
//   ph6: rd fa1L+fa1H (b1,k1) [8]                           ; MFMA Q6
//   ph7: (no reads)          ; stage A(T+3)->buf1 ; vmcnt(4); MFMA Q7
//   ph8: rd fa0L+fb0 (b0',k0) [8]                           ; MFMA Q8
//
// vmcnt ledger (4 gloads per stage call; entry = A(T+1) = 4):
//   ph1 +4=8 ; ph3 +4=12 -> vmcnt(4) drains A(T+1)+B(T+1): buf1 tile T+1
//     complete before ph4's reads. leaves B(T+2)=4.
//   ph4 +4=8 ; ph7 +4=12 -> vmcnt(4) drains B(T+2)+A(T+2): buf0 tile T+2
//     complete before ph8's reads. leaves A(T+3)=4 = entry invariant.
//   All waited loads are >=2 windows old (>= ~1600 cyc > 900 HBM latency).
// LDS WAR (stage >=1 window after region's last read; reads complete at
// their window's lgkm(0) before its BAR):
//   B(T+1)->buf1.B @ph1: last read prev ph5 (fb1 b1). OK
//   B(T+2)->buf0.B @ph3: last read ph1 (fb1 b0). OK
//   A(T+2)->buf0.A @ph4: last read ph3 (fa1H b0). OK
//   A(T+3)->buf1.A @ph7: last read ph6 (fa1 b1). OK
// Register WAR (write set disjoint from current MFMA's reads; last use >=1
// window before rewrite): fa0L used Q1/Q5, rewritten ph4/ph8; fa0H used
// Q2/Q6, rewritten ph1/ph5; fa1 used Q3,Q4/Q7,Q8, rewritten ph2,ph3/ph6;
// fb0 used Q1,Q2/Q5,Q6, rewritten ph4/ph8; fb1 used Q3,Q4/Q7,Q8, rewritten
// ph1/ph5. All static indices (rule #20).
// Tail: tS2/tS3 clamp to NT-1; dummy stages land in windows per the same
// WAR audit (last-iter ph7 rewrites buf1.A with identical bytes); last-iter
// ph8 reads dummy data into fragments never consumed. Uniform control flow,
// vmcnt always satisfiable; final vmcnt(0) drains dummies.
//
// LDS swizzle (both-sides, rule #21) unchanged (bank conflicts = 0).
// ===========================================================================
constexpr int BM2 = 256, BN2 = 256, BK2 = 64;

#define SB()    __builtin_amdgcn_sched_barrier(0)
#define BAR()   __builtin_amdgcn_s_barrier()
#define LGKM0() asm volatile("s_waitcnt lgkmcnt(0)" ::: "memory")
#define VMCNT(N) asm volatile("s_waitcnt vmcnt(" #N ")" ::: "memory")

#define MFMA_HALF(A, B, IBASE)                                             \
    _Pragma("unroll")                                                      \
    for (int i_ = 0; i_ < 4; ++i_) {                                       \
        _Pragma("unroll")                                                  \
        for (int j_ = 0; j_ < 4; ++j_)                                     \
            acc[(IBASE) + i_][j_] = __builtin_amdgcn_mfma_f32_16x16x32_bf16( \
                (A)[(IBASE) + i_], (B)[j_], acc[(IBASE) + i_][j_], 0, 0, 0); \
    }

// phase tail: pin issue order (reads/stages already issued), run MFMA hot,
// drain LDS reads under/after MFMA, one barrier, crisp phase boundary.
#define PHASE_TAIL(A, B, IBASE)                          \
    SB();                                                \
    __builtin_amdgcn_s_setprio(1);                       \
    MFMA_HALF(A, B, IBASE);                              \
    __builtin_amdgcn_s_setprio(0);                       \
    LGKM0();                                             \
    BAR();                                               \
    SB()

#define PHASE_TAIL_VM4(A, B, IBASE)                      \
    SB();                                                \
    __builtin_amdgcn_s_setprio(1);                       \
    MFMA_HALF(A, B, IBASE);                              \
    __builtin_amdgcn_s_setprio(0);                       \
    LGKM0();                                             \
    VMCNT(4);                                            \
    BAR();                                               \
    SB()

// 4 A-fragment reads [LO, LO+4) for kk-half KH of buffer BUF (static args)
#define READ_A4(DST, BUF, KH, LO)                                          \
    _Pragma("unroll")                                                      \
    for (int i_ = (LO); i_ < (LO) + 4; ++i_)                               \
        DST[i_] = *(const bf16x8*)(&As[BUF][(wm * 128 + i_ * 16 + lrow) * 64 \
                                           + (((lhi + 4 * (KH)) ^ swz) * 8)]);
#define READ_B4(DST, BUF, KH)                                              \
    _Pragma("unroll")                                                      \
    for (int j_ = 0; j_ < 4; ++j_)                                         \
        DST[j_] = *(const bf16x8*)(&Bs[BUF][(wn * 64 + j_ * 16 + lrow) * 64 \
                                           + (((lhi + 4 * (KH)) ^ swz) * 8)]);

__global__ __launch_bounds__(512, 2)
void gemm8_kernel(const bf16* __restrict__ Ab,   // [M][K] bf16
                  const bf16* __restrict__ Bt,   // [K/64][N][64] bf16 (= W^T k-tiled)
                  const float* __restrict__ bias,
                  float* __restrict__ out,
                  int M, int N, int K, int nbx) {
    __shared__ __align__(16) bf16 As[2][BM2 * BK2];   // 2 x 32KB
    __shared__ __align__(16) bf16 Bs[2][BN2 * BK2];   // 2 x 32KB

    const int tid  = threadIdx.x;
    const int lane = tid & 63;
    const int wave = tid >> 6;
    const int wm = wave >> 2;        // 0..1
    const int wn = wave & 3;         // 0..3

    // T1: bijective XCD swizzle (m204), column-fast (unchanged).
    const int nwg = gridDim.x;
    int wg = blockIdx.x;
    {
        const int q = nwg >> 3, r = nwg & 7;
        const int xcd = wg & 7, off = wg >> 3;
        wg = (xcd < r ? xcd * (q + 1) : r * (q + 1) + (xcd - r) * q) + off;
    }
    const int nby = nwg / nbx;
    const int bx = wg / nby;
    const int by = wg % nby;
    const int m0 = by * BM2;
    const int n0 = bx * BN2;

    const int lrow = lane & 15;
    const int lhi  = lane >> 4;
    const int swz  = (lrow >> 1) & 7;

    const int NT = K >> 6;           // K-tiles
    const int NI = NT >> 1;          // iterations (2 tiles each); K%128==0 guaranteed

    // --- precomputed staging addresses (HK technique 8): src base pointers
    // per (half, it); per call: base + tIdx*stride (32-bit mul + 64-bit add).
    const bf16* aSrc[2][2];
    const bf16* bSrc[2][2];
#pragma unroll
    for (int h = 0; h < 2; ++h)
#pragma unroll
        for (int it = 0; it < 2; ++it) {
            const int q  = tid + it * 512;              // chunk in half-tile
            const int rl = q >> 3;                      // row within half
            const int cl = (q & 7) ^ ((rl >> 1) & 7);   // inverse-swizzled src chunk
            aSrc[h][it] = Ab + (size_t)(m0 + h * 128 + rl) * K + cl * 8;
            bSrc[h][it] = Bt + (size_t)(n0 + h * 128 + rl) * 64 + cl * 8;
        }
    const size_t aStride = 64;                  // elems per K-tile along a row
    const size_t bStride = (size_t)N * 64;      // elems per K-tile in Wt

    auto stageA = [&](int tIdx, int buf) {      // both halves: 4 gloads
#pragma unroll
        for (int h = 0; h < 2; ++h)
#pragma unroll
            for (int it = 0; it < 2; ++it) {
                const int q = tid + it * 512;
                gload_lds16(aSrc[h][it] + (size_t)tIdx * aStride,
                            &As[buf][h * 8192 + q * 8]);   // linear LDS dest
            }
    };
    auto stageB = [&](int tIdx, int buf) {
#pragma unroll
        for (int h = 0; h < 2; ++h)
#pragma unroll
            for (int it = 0; it < 2; ++it) {
                const int q = tid + it * 512;
                gload_lds16(bSrc[h][it] + (size_t)tIdx * bStride,
                            &Bs[buf][h * 8192 + q * 8]);
            }
    };

    f32x4 acc[8][4];
#pragma unroll
    for (int i = 0; i < 8; ++i)
#pragma unroll
        for (int j = 0; j < 4; ++j) acc[i][j] = (f32x4){0.f, 0.f, 0.f, 0.f};

    // prologue: tile0 -> buf0 (8 loads) + A(1) -> buf1 (4 loads)
    stageA(0, 0); stageB(0, 0); stageA(1, 1);
    VMCNT(4);                         // tile0 landed; A(1)=4 in flight
    BAR();
    SB();

    bf16x8 fa0[8], fa1[8], fb0[4], fb1[4];
    READ_A4(fa0, 0, 0, 0);            // Q1 fragments (ph8-equivalent)
    READ_B4(fb0, 0, 0);

    for (int i2 = 0; i2 < NI; ++i2) {
        const int t0  = 2 * i2;
        const int tB1 = t0 + 1;                           // buf1 tile (< NT always)
        const int tS2 = (t0 + 2 < NT) ? t0 + 2 : NT - 1;  // clamped dummy at tail
        const int tS3 = (t0 + 3 < NT) ? t0 + 3 : NT - 1;

        // ph1: rd fa0H(b0,k0)+fb1(b0,k1); stage B(T+1)->buf1; MFMA Q1
        READ_A4(fa0, 0, 0, 4);
        READ_B4(fb1, 0, 1);
        stageB(tB1, 1);
        PHASE_TAIL(fa0, fb0, 0);

        // ph2: rd fa1L(b0,k1); MFMA Q2
        READ_A4(fa1, 0, 1, 0);
        PHASE_TAIL(fa0, fb0, 4);

        // ph3: rd fa1H(b0,k1); stage B(T+2)->buf0; MFMA Q3; vmcnt(4)
        READ_A4(fa1, 0, 1, 4);
        stageB(tS2, 0);
        PHASE_TAIL_VM4(fa1, fb1, 0);   // drains A(T+1)+B(T+1): buf1 ready

        // ph4: rd fa0L+fb0 (b1,k0); stage A(T+2)->buf0; MFMA Q4
        READ_A4(fa0, 1, 0, 0);
        READ_B4(fb0, 1, 0);
        stageA(tS2, 0);
        PHASE_TAIL(fa1, fb1, 4);

        // ph5: rd fa0H(b1,k0)+fb1(b1,k1); MFMA Q5
        READ_A4(fa0, 1, 0, 4);
        READ_B4(fb1, 1, 1);
        PHASE_TAIL(fa0, fb0, 0);

        // ph6: rd fa1L+fa1H (b1,k1); MFMA Q6
        READ_A4(fa1, 1, 1, 0);
        READ_A4(fa1, 1, 1, 4);
        PHASE_TAIL(fa0, fb0, 4);

        // ph7: stage A(T+3)->buf1; MFMA Q7; vmcnt(4)
        stageA(tS3, 1);
        PHASE_TAIL_VM4(fa1, fb1, 0);   // drains B(T+2)+A(T+2): buf0 ready

        // ph8: rd fa0L+fb0 (b0',k0 = tile T+2); MFMA Q8
        READ_A4(fa0, 0, 0, 0);
        READ_B4(fb0, 0, 0);
        PHASE_TAIL(fa1, fb1, 4);
    }

    asm volatile("s_waitcnt vmcnt(0)" ::: "memory");   // drain before LDS dealloc

    // epilogue: D layout col=lane&15 (n), row=(lane>>4)*4+reg (m); f32 out
#pragma unroll
    for (int j = 0; j < 4; ++j) {
        const int col = n0 + wn * 64 + j * 16 + lrow;
        const float bv = bias[col];
#pragma unroll
        for (int i = 0; i < 8; ++i) {
            const int rbase = m0 + wm * 128 + i * 16 + lhi * 4;
#pragma unroll
            for (int r = 0; r < 4; ++r)
                out[(size_t)(rbase + r) * N + col] = acc[i][j][r] + bv;
        }
    }
}

// ---------------------------------------------------------------------------
// FUSED fallback (small-ws only): f32 x + qweight dequant in-flight.
// 128x128 tile, BK=32, 4 waves (2x2), 4x4 of mfma_f32_16x16x32_bf16.
// ---------------------------------------------------------------------------
constexpr int BM = 128, BN = 128, BK = 32;

__global__ __launch_bounds__(256)
void gemm_fused_kernel(const float* __restrict__ Af,      // [M,K] f32
                       const uint32_t* __restrict__ qw,   // [K/8,N]
                       const float* __restrict__ scales,  // [K/G,N] f32
                       const float* __restrict__ qzeros,  // [K/G,N] f32
                       const float* __restrict__ bias,    // [N] f32
                       float* __restrict__ out,           // [M,N] f32
                       int M, int N, int K, int G) {
    __shared__ __align__(16) bf16 As2[BM * BK];
    __shared__ __align__(16) bf16 Bs2[BN * BK];

    const int tid  = threadIdx.x;
    const int lane = tid & 63;
    const int wave = tid >> 6;
    const int wmm = wave & 1;
    const int wnn = wave >> 1;
    const int m0 = blockIdx.y * BM;
    const int n0 = blockIdx.x * BN;

    const int lr = lane & 15;
    const int lk8 = (lane >> 4) * 8;

    f32x4 acc[4][4];
#pragma unroll
    for (int i = 0; i < 4; ++i)
#pragma unroll
        for (int j = 0; j < 4; ++j) acc[i][j] = (f32x4){0.f, 0.f, 0.f, 0.f};

    for (int kt = 0; kt < K; kt += BK) {
#pragma unroll
        for (int it = 0; it < 2; ++it) {
            const int c = tid + it * 256;
            const int row = c >> 2;
            const int kc  = (c & 3) * 8;
            const f32x4* p = (const f32x4*)(Af + (size_t)(m0 + row) * K + kt + kc);
            f32x4 a = p[0], b = p[1];
            bf16x8 v;
#pragma unroll
            for (int j = 0; j < 4; ++j) { v[j] = (bf16)a[j]; v[4 + j] = (bf16)b[j]; }
            *(bf16x8*)(As2 + row * BK + kc) = v;
        }
        const int g = kt / G;
#pragma unroll
        for (int it = 0; it < 2; ++it) {
            const int idx = tid + it * 256;
            const int rl = idx >> 7;
            const int nl = idx & 127;
            uint32_t q = qw[(size_t)(kt / 8 + rl) * N + n0 + nl];
            float s = scales[(size_t)g * N + n0 + nl];
            float z = qzeros[(size_t)g * N + n0 + nl];
            float nsz = -s * z;
            bf16x8 v;
#pragma unroll
            for (int j = 0; j < 8; ++j)
                v[j] = (bf16)fmaf((float)((q >> (4 * j)) & 15u), s, nsz);
            *(bf16x8*)(Bs2 + nl * BK + rl * 8) = v;
        }
        __syncthreads();

        bf16x8 a[4], b[4];
#pragma unroll
        for (int i = 0; i < 4; ++i)
            a[i] = *(const bf16x8*)(As2 + (wmm * 64 + i * 16 + lr) * BK + lk8);
#pragma unroll
        for (int j = 0; j < 4; ++j)
            b[j] = *(const bf16x8*)(Bs2 + (wnn * 64 + j * 16 + lr) * BK + lk8);

#pragma unroll
        for (int i = 0; i < 4; ++i)
#pragma unroll
            for (int j = 0; j < 4; ++j)
                acc[i][j] = __builtin_amdgcn_mfma_f32_16x16x32_bf16(
                    a[i], b[j], acc[i][j], 0, 0, 0);
        __syncthreads();
    }

#pragma unroll
    for (int j = 0; j < 4; ++j) {
        const int col = n0 + wnn * 64 + j * 16 + (lane & 15);
        const float bv = bias[col];
#pragma unroll
        for (int i = 0; i < 4; ++i) {
            const int rbase = m0 + wmm * 64 + i * 16 + (lane >> 4) * 4;
#pragma unroll
            for (int r = 0; r < 4; ++r)
                out[(size_t)(rbase + r) * N + col] = acc[i][j][r] + bv;
        }
    }
}

extern "C" void kernel_launch(void* const* d_in, const int* in_sizes, int n_in,
                              void* d_out, int out_size, void* d_ws, size_t ws_size,
                              hipStream_t stream) {
    // fp16 reference tensors are stored as FLOAT32 by the harness
    const float*    x      = (const float*)d_in[0];
    const uint32_t* qw     = (const uint32_t*)d_in[1];
    const float*    scales = (const float*)d_in[2];
    const float*    qzeros = (const float*)d_in[3];
    const float*    bias   = (const float*)d_in[4];
    float*          out    = (float*)d_out;

    const int N = in_sizes[4];                 // 4096
    const int K = (in_sizes[1] / N) * 8;       // 4096
    const int M = in_sizes[0] / K;             // 8192
    const int G = K / (in_sizes[2] / N);       // 64

    const size_t xb_bytes = (size_t)M * K * sizeof(bf16);   // 64 MB
    const size_t wt_bytes = (size_t)N * K * sizeof(bf16);   // 32 MB

    const bool shape_ok = (M % BM2 == 0) && (N % BN2 == 0) && (K % 128 == 0) &&
                          (G % 8 == 0);

    if (shape_ok && ws_size >= xb_bytes + wt_bytes) {
        bf16* Xb = (bf16*)d_ws;
        bf16* Wt = (bf16*)((char*)d_ws + xb_bytes);
        const long n8 = (long)M * K / 8;
        convert_x_kernel<<<(int)((n8 + 255) / 256), 256, 0, stream>>>(x, Xb, n8);
        // waves = (K/64) * (N/8); threads = waves*64
        const long dq_threads = ((long)K >> 6) * (N / 8) * 64;
        dequant_wt64_kernel<<<(int)((dq_threads + 255) / 256), 256, 0, stream>>>(
            qw, scales, qzeros, Wt, N, K, G / 8);
        const int nbx = N / BN2;
        const int nwg = nbx * (M / BM2);       // 512
        gemm8_kernel<<<nwg, 512, 0, stream>>>(Xb, Wt, bias, out, M, N, K, nbx);
    } else {
        dim3 grid(N / BN, M / BM);
        gemm_fused_kernel<<<grid, 256, 0, stream>>>(
            x, qw, scales, qzeros, bias, out, M, N, K, G);
    }
}

// Round 7
// 478.687 us; speedup vs baseline: 1.0826x; 1.0826x over previous
//
#include <hip/hip_runtime.h>
#include <stdint.h>
#include <stddef.h>

typedef __bf16 bf16;
typedef __bf16 bf16x8 __attribute__((ext_vector_type(8)));
typedef float  f32x4  __attribute__((ext_vector_type(4)));

#define GLOBAL_AS(p) ((const __attribute__((address_space(1))) void*)(p))
#define LDS_AS(p)    ((__attribute__((address_space(3))) void*)(p))

__device__ __forceinline__ void gload_lds16(const bf16* g, bf16* l) {
    // global_load_lds_dwordx4: LDS dest = wave-uniform base + lane*16 (caller guarantees)
    __builtin_amdgcn_global_load_lds(GLOBAL_AS(g), LDS_AS(l), 16, 0, 0);
}

// ---------------------------------------------------------------------------
// x (f32) -> bf16, 8 elems/thread, both directions coalesced
// ---------------------------------------------------------------------------
__global__ __launch_bounds__(256)
void convert_x_kernel(const float* __restrict__ x, bf16* __restrict__ xb, long n8) {
    long t = (long)blockIdx.x * blockDim.x + threadIdx.x;
    if (t >= n8) return;
    const f32x4* p = (const f32x4*)(x + t * 8);
    f32x4 a = p[0], b = p[1];
    bf16x8 v;
#pragma unroll
    for (int j = 0; j < 4; ++j) { v[j] = (bf16)a[j]; v[4 + j] = (bf16)b[j]; }
    *(bf16x8*)(xb + t * 8) = v;
}

// ---------------------------------------------------------------------------
// Dequant to K-TILED layout for BK=64: Wt[K/64][N][64], Wt[t][o][cc] = W^T[o][t*64+cc]
// ---------------------------------------------------------------------------
__global__ __launch_bounds__(256)
void dequant_wt64_kernel(const uint32_t* __restrict__ qw,
                         const float* __restrict__ scales,
                         const float* __restrict__ qzeros,
                         bf16* __restrict__ Wt,
                         int N, int K, int rows_per_group) {
    const int i = blockIdx.x * 256 + threadIdx.x;
    const int w = i >> 6, l = i & 63;
    const int nr8 = K >> 6;                  // 8-row groups (64 k each)
    const int r8 = w % nr8;
    const int o  = (w / nr8) * 8 + (l >> 3);
    const int rr = l & 7;
    const int r  = r8 * 8 + rr;              // qweight row; k = r*8 + j
    if (o >= N) return;
    const uint32_t q = qw[(size_t)r * N + o];
    const int g = r / rows_per_group;
    const float s = scales[(size_t)g * N + o];
    const float z = qzeros[(size_t)g * N + o];
    const float nsz = -s * z;
    bf16x8 v;
#pragma unroll
    for (int j = 0; j < 8; ++j)
        v[j] = (bf16)fmaf((float)((q >> (4 * j)) & 15u), s, nsz);
    *(bf16x8*)(Wt + ((size_t)r8 * N + o) * 64 + rr * 8) = v;
}

// ===========================================================================
// 256x256 8-phase GEMM — SCHEDULE M (m201-convergent: front-loaded tile reads,
// compiler partial-lgkm pipelining, 1 half-tile stage/phase, vmcnt(4) @ph4/8).
//
// R6 diagnosis: P/P2's per-phase lgkm(0) drains re-serialized LDS vs MFMA.
// Fix derived by closing ALL m201 template constraints:
//   - ALL 24 ds_reads of a K-tile issue in its first two phases (12+12).
//     Compiler inserts exact partial lgkm waits per MFMA quantum (m97
//     evidence) -> Q1 starts after its 8 frags; remaining reads drain UNDER
//     the MFMA stream of ph1-4 (LDS pipe continuously busy, no lockstep).
//   - Regions free early: B after ph2-end lgkmcnt(8) (B-reads pinned BEFORE
//     A-reads in ph2 via sched_barrier), A after ph4-end lgkmcnt(0).
//   - Stages: exactly 1 half-tile (2 gloads) per phase:
//       ph1: O.A0->buf1   ph2: O.A1->buf1   ph3: E2.B0->buf0  ph4: E2.B1->buf0
//       ph5: E2.A0->buf0  ph6: E2.A1->buf0  ph7: O2.B0->buf1  ph8: O2.B1->buf1
//     (E=2i read buf0 ph1-4; O=E+1 read buf1 ph5-8; E2=E+2, O2=E+3 clamped)
//   - vmcnt(4) at ph4 and ph8 ONLY. Ledger (2 loads/phase):
//       enter ph1: 4 (O.B0,B1 from prev ph7,8)
//       ph1..ph4: +2 each -> 12; vmcnt(4) drains O.B0,B1,A0,A1 -> O complete
//         before ph5 reads buf1; leaves E2.B0,B1 (4).
//       ph5..ph8: +2 each -> 12; vmcnt(4) drains E2's 4 halves -> buf0
//         complete before next ph1; leaves O2.B0,B1 (4) = invariant.
//   - LDS-region WAR (stage after lgkm-level+barrier retiring last reader):
//       O.A0/A1 @ph1/2: buf1.A last read prev ph6, drained prev-ph8 lgkm(0). OK
//       E2.B0/B1 @ph3/4: buf0.B reads ph1(fb0)+ph2(fb1, pinned first),
//         drained by ph2-end lgkm(8). OK
//       E2.A0/A1 @ph5/6: buf0.A reads ph1/ph2, drained ph4-end lgkm(0). OK
//       O2.B0/B1 @ph7/8: buf1.B reads ph5+ph6(pinned first), ph6-end lgkm(8). OK
//   - Register WAR: fa0/fb0 last MFMA use ph2/ph6, rewritten ph5/ph1';
//     fa1/fb1 last use ph4/ph8, rewritten ph6/ph2'. Static indices (rule #20).
//   - DS ops retire in order per wave; the lgkm(8) region-frees rely only on
//     B-reads preceding A-reads within ph2/ph6 (pinned by sched_barrier).
//   - Tail: E2/O2 clamp to NT-1; dummy stages land after the same read
//     windows; last-iter reads feed never-consumed fragments. Uniform flow,
//     waits satisfiable; final vmcnt(0).
//
// LDS swizzle (both-sides, rule #21) unchanged (bank conflicts = 0).
// ===========================================================================
constexpr int BM2 = 256, BN2 = 256, BK2 = 64;

#define SB()    __builtin_amdgcn_sched_barrier(0)
#define BAR()   __builtin_amdgcn_s_barrier()
#define LGKM(N) asm volatile("s_waitcnt lgkmcnt(" #N ")" ::: "memory")
#define VMCNT(N) asm volatile("s_waitcnt vmcnt(" #N ")" ::: "memory")
#define PRIO1() __builtin_amdgcn_s_setprio(1)
#define PRIO0() __builtin_amdgcn_s_setprio(0)

#define MFMA_HALF(A, B, IBASE)                                             \
    _Pragma("unroll")                                                      \
    for (int i_ = 0; i_ < 4; ++i_) {                                       \
        _Pragma("unroll")                                                  \
        for (int j_ = 0; j_ < 4; ++j_)                                     \
            acc[(IBASE) + i_][j_] = __builtin_amdgcn_mfma_f32_16x16x32_bf16( \
                (A)[(IBASE) + i_], (B)[j_], acc[(IBASE) + i_][j_], 0, 0, 0); \
    }

// 4 A-fragment reads [LO, LO+4) for kk-half KH of buffer BUF (static args)
#define READ_A4(DST, BUF, KH, LO)                                          \
    _Pragma("unroll")                                                      \
    for (int i_ = (LO); i_ < (LO) + 4; ++i_)                               \
        DST[i_] = *(const bf16x8*)(&As[BUF][(wm * 128 + i_ * 16 + lrow) * 64 \
                                           + (((lhi + 4 * (KH)) ^ swz) * 8)]);
#define READ_B4(DST, BUF, KH)                                              \
    _Pragma("unroll")                                                      \
    for (int j_ = 0; j_ < 4; ++j_)                                         \
        DST[j_] = *(const bf16x8*)(&Bs[BUF][(wn * 64 + j_ * 16 + lrow) * 64 \
                                           + (((lhi + 4 * (KH)) ^ swz) * 8)]);

__global__ __launch_bounds__(512, 2)
void gemm8_kernel(const bf16* __restrict__ Ab,   // [M][K] bf16
                  const bf16* __restrict__ Bt,   // [K/64][N][64] bf16 (= W^T k-tiled)
                  const float* __restrict__ bias,
                  float* __restrict__ out,
                  int M, int N, int K, int nbx) {
    __shared__ __align__(16) bf16 As[2][BM2 * BK2];   // 2 x 32KB
    __shared__ __align__(16) bf16 Bs[2][BN2 * BK2];   // 2 x 32KB

    const int tid  = threadIdx.x;
    const int lane = tid & 63;
    const int wave = tid >> 6;
    const int wm = wave >> 2;        // 0..1
    const int wn = wave & 3;         // 0..3

    // T1: bijective XCD swizzle (m204), column-fast (unchanged).
    const int nwg = gridDim.x;
    int wg = blockIdx.x;
    {
        const int q = nwg >> 3, r = nwg & 7;
        const int xcd = wg & 7, off = wg >> 3;
        wg = (xcd < r ? xcd * (q + 1) : r * (q + 1) + (xcd - r) * q) + off;
    }
    const int nby = nwg / nbx;
    const int bx = wg / nby;
    const int by = wg % nby;
    const int m0 = by * BM2;
    const int n0 = bx * BN2;

    const int lrow = lane & 15;
    const int lhi  = lane >> 4;
    const int swz  = (lrow >> 1) & 7;

    const int NT = K >> 6;           // K-tiles (64)
    const int NI = NT >> 1;          // iterations; K%128==0 guaranteed

    // precomputed staging source pointers (per half, per it)
    const bf16* aSrc[2][2];
    const bf16* bSrc[2][2];
#pragma unroll
    for (int h = 0; h < 2; ++h)
#pragma unroll
        for (int it = 0; it < 2; ++it) {
            const int q  = tid + it * 512;              // chunk in half-tile
            const int rl = q >> 3;                      // row within half
            const int cl = (q & 7) ^ ((rl >> 1) & 7);   // inverse-swizzled src chunk
            aSrc[h][it] = Ab + (size_t)(m0 + h * 128 + rl) * K + cl * 8;
            bSrc[h][it] = Bt + (size_t)(n0 + h * 128 + rl) * 64 + cl * 8;
        }
    const size_t aStride = 64;                  // elems per K-tile along an A row
    const size_t bStride = (size_t)N * 64;      // elems per K-tile in Wt

    auto stageAh = [&](int tIdx, int half, int buf) {   // one half-tile: 2 gloads
#pragma unroll
        for (int it = 0; it < 2; ++it) {
            const int q = tid + it * 512;
            gload_lds16(aSrc[half][it] + (size_t)tIdx * aStride,
                        &As[buf][half * 8192 + q * 8]);   // linear LDS dest
        }
    };
    auto stageBh = [&](int tIdx, int half, int buf) {
#pragma unroll
        for (int it = 0; it < 2; ++it) {
            const int q = tid + it * 512;
            gload_lds16(bSrc[half][it] + (size_t)tIdx * bStride,
                        &Bs[buf][half * 8192 + q * 8]);
        }
    };

    f32x4 acc[8][4];
#pragma unroll
    for (int i = 0; i < 8; ++i)
#pragma unroll
        for (int j = 0; j < 4; ++j) acc[i][j] = (f32x4){0.f, 0.f, 0.f, 0.f};

    // prologue: tile0 (buf0, 8 loads) + tile1.B halves (buf1, 4 loads)
    stageAh(0, 0, 0); stageAh(0, 1, 0); stageBh(0, 0, 0); stageBh(0, 1, 0);
    stageBh(1, 0, 1); stageBh(1, 1, 1);
    VMCNT(4);                         // tile0 landed; O.B0,B1 in flight (=4)
    BAR();
    SB();

    bf16x8 fa0[8], fa1[8], fb0[4], fb1[4];

    for (int i2 = 0; i2 < NI; ++i2) {
        const int tE  = 2 * i2;
        const int tO  = tE + 1;                           // < NT always
        const int tE2 = (tE + 2 < NT) ? tE + 2 : NT - 1;  // clamped dummy at tail
        const int tO2 = (tE + 3 < NT) ? tE + 3 : NT - 1;

        // ---- ph1: ALL k0 reads (buf0) ; stage O.A0->buf1 ; MFMA Q1(k0,i0-3)
        READ_A4(fa0, 0, 0, 0);        // Q1 A frags first (tightest wait)
        READ_B4(fb0, 0, 0);           // Q1 B frags
        READ_A4(fa0, 0, 0, 4);        // Q2 A frags
        stageAh(tO, 0, 1);
        SB();
        PRIO1(); MFMA_HALF(fa0, fb0, 0); PRIO0();
        BAR(); SB();

        // ---- ph2: ALL k1 reads (buf0), B FIRST ; stage O.A1 ; MFMA Q2(k0,i4-7)
        READ_B4(fb1, 0, 1);           // B-reads pinned before A-reads
        SB();                         // (region-free lgkm(8) depends on order)
        READ_A4(fa1, 0, 1, 0);
        READ_A4(fa1, 0, 1, 4);
        stageAh(tO, 1, 1);
        SB();
        PRIO1(); MFMA_HALF(fa0, fb0, 4); PRIO0();
        LGKM(8); SB();                // <=8 outstanding = fa1 reads -> buf0.B free
        BAR(); SB();

        // ---- ph3: stage E2.B0->buf0 ; MFMA Q3(k1,i0-3)
        stageBh(tE2, 0, 0);
        SB();
        PRIO1(); MFMA_HALF(fa1, fb1, 0); PRIO0();
        BAR(); SB();

        // ---- ph4: stage E2.B1->buf0 ; MFMA Q4(k1,i4-7) ; free A ; vmcnt(4)
        stageBh(tE2, 1, 0);
        SB();
        PRIO1(); MFMA_HALF(fa1, fb1, 4); PRIO0();
        LGKM(0); SB();                // buf0.A free
        VMCNT(4);                     // O tile (B0,B1,A0,A1) fully landed
        BAR(); SB();

        // ---- ph5: ALL k0 reads (buf1) ; stage E2.A0->buf0 ; MFMA Q5
        READ_A4(fa0, 1, 0, 0);
        READ_B4(fb0, 1, 0);
        READ_A4(fa0, 1, 0, 4);
        stageAh(tE2, 0, 0);
        SB();
        PRIO1(); MFMA_HALF(fa0, fb0, 0); PRIO0();
        BAR(); SB();

        // ---- ph6: ALL k1 reads (buf1), B first ; stage E2.A1 ; MFMA Q6
        READ_B4(fb1, 1, 1);
        SB();
        READ_A4(fa1, 1, 1, 0);
        READ_A4(fa1, 1, 1, 4);
        stageAh(tE2, 1, 0);
        SB();
        PRIO1(); MFMA_HALF(fa0, fb0, 4); PRIO0();
        LGKM(8); SB();                // buf1.B free
        BAR(); SB();

        // ---- ph7: stage O2.B0->buf1 ; MFMA Q7
        stageBh(tO2, 0, 1);
        SB();
        PRIO1(); MFMA_HALF(fa1, fb1, 0); PRIO0();
        BAR(); SB();

        // ---- ph8: stage O2.B1->buf1 ; MFMA Q8 ; free A ; vmcnt(4)
        stageBh(tO2, 1, 1);
        SB();
        PRIO1(); MFMA_HALF(fa1, fb1, 4); PRIO0();
        LGKM(0); SB();                // buf1.A free
        VMCNT(4);                     // E2 tile fully landed
        BAR(); SB();
    }

    asm volatile("s_waitcnt vmcnt(0)" ::: "memory");   // drain dummies

    // epilogue: D layout col=lane&15 (n), row=(lane>>4)*4+reg (m); f32 out
#pragma unroll
    for (int j = 0; j < 4; ++j) {
        const int col = n0 + wn * 64 + j * 16 + lrow;
        const float bv = bias[col];
#pragma unroll
        for (int i = 0; i < 8; ++i) {
            const int rbase = m0 + wm * 128 + i * 16 + lhi * 4;
#pragma unroll
            for (int r = 0; r < 4; ++r)
                out[(size_t)(rbase + r) * N + col] = acc[i][j][r] + bv;
        }
    }
}

// ---------------------------------------------------------------------------
// FUSED fallback (small-ws only): f32 x + qweight dequant in-flight.
// 128x128 tile, BK=32, 4 waves (2x2), 4x4 of mfma_f32_16x16x32_bf16.
// ---------------------------------------------------------------------------
constexpr int BM = 128, BN = 128, BK = 32;

__global__ __launch_bounds__(256)
void gemm_fused_kernel(const float* __restrict__ Af,      // [M,K] f32
                       const uint32_t* __restrict__ qw,   // [K/8,N]
                       const float* __restrict__ scales,  // [K/G,N] f32
                       const float* __restrict__ qzeros,  // [K/G,N] f32
                       const float* __restrict__ bias,    // [N] f32
                       float* __restrict__ out,           // [M,N] f32
                       int M, int N, int K, int G) {
    __shared__ __align__(16) bf16 As2[BM * BK];
    __shared__ __align__(16) bf16 Bs2[BN * BK];

    const int tid  = threadIdx.x;
    const int lane = tid & 63;
    const int wave = tid >> 6;
    const int wmm = wave & 1;
    const int wnn = wave >> 1;
    const int m0 = blockIdx.y * BM;
    const int n0 = blockIdx.x * BN;

    const int lr = lane & 15;
    const int lk8 = (lane >> 4) * 8;

    f32x4 acc[4][4];
#pragma unroll
    for (int i = 0; i < 4; ++i)
#pragma unroll
        for (int j = 0; j < 4; ++j) acc[i][j] = (f32x4){0.f, 0.f, 0.f, 0.f};

    for (int kt = 0; kt < K; kt += BK) {
#pragma unroll
        for (int it = 0; it < 2; ++it) {
            const int c = tid + it * 256;
            const int row = c >> 2;
            const int kc  = (c & 3) * 8;
            const f32x4* p = (const f32x4*)(Af + (size_t)(m0 + row) * K + kt + kc);
            f32x4 a = p[0], b = p[1];
            bf16x8 v;
#pragma unroll
            for (int j = 0; j < 4; ++j) { v[j] = (bf16)a[j]; v[4 + j] = (bf16)b[j]; }
            *(bf16x8*)(As2 + row * BK + kc) = v;
        }
        const int g = kt / G;
#pragma unroll
        for (int it = 0; it < 2; ++it) {
            const int idx = tid + it * 256;
            const int rl = idx >> 7;
            const int nl = idx & 127;
            uint32_t q = qw[(size_t)(kt / 8 + rl) * N + n0 + nl];
            float s = scales[(size_t)g * N + n0 + nl];
            float z = qzeros[(size_t)g * N + n0 + nl];
            float nsz = -s * z;
            bf16x8 v;
#pragma unroll
            for (int j = 0; j < 8; ++j)
                v[j] = (bf16)fmaf((float)((q >> (4 * j)) & 15u), s, nsz);
            *(bf16x8*)(Bs2 + nl * BK + rl * 8) = v;
        }
        __syncthreads();

        bf16x8 a[4], b[4];
#pragma unroll
        for (int i = 0; i < 4; ++i)
            a[i] = *(const bf16x8*)(As2 + (wmm * 64 + i * 16 + lr) * BK + lk8);
#pragma unroll
        for (int j = 0; j < 4; ++j)
            b[j] = *(const bf16x8*)(Bs2 + (wnn * 64 + j * 16 + lr) * BK + lk8);

#pragma unroll
        for (int i = 0; i < 4; ++i)
#pragma unroll
            for (int j = 0; j < 4; ++j)
                acc[i][j] = __builtin_amdgcn_mfma_f32_16x16x32_bf16(
                    a[i], b[j], acc[i][j], 0, 0, 0);
        __syncthreads();
    }

#pragma unroll
    for (int j = 0; j < 4; ++j) {
        const int col = n0 + wnn * 64 + j * 16 + (lane & 15);
        const float bv = bias[col];
#pragma unroll
        for (int i = 0; i < 4; ++i) {
            const int rbase = m0 + wmm * 64 + i * 16 + (lane >> 4) * 4;
#pragma unroll
            for (int r = 0; r < 4; ++r)
                out[(size_t)(rbase + r) * N + col] = acc[i][j][r] + bv;
        }
    }
}

extern "C" void kernel_launch(void* const* d_in, const int* in_sizes, int n_in,
                              void* d_out, int out_size, void* d_ws, size_t ws_size,
                              hipStream_t stream) {
    // fp16 reference tensors are stored as FLOAT32 by the harness
    const float*    x      = (const float*)d_in[0];
    const uint32_t* qw     = (const uint32_t*)d_in[1];
    const float*    scales = (const float*)d_in[2];
    const float*    qzeros = (const float*)d_in[3];
    const float*    bias   = (const float*)d_in[4];
    float*          out    = (float*)d_out;

    const int N = in_sizes[4];                 // 4096
    const int K = (in_sizes[1] / N) * 8;       // 4096
    const int M = in_sizes[0] / K;             // 8192
    const int G = K / (in_sizes[2] / N);       // 64

    const size_t xb_bytes = (size_t)M * K * sizeof(bf16);   // 64 MB
    const size_t wt_bytes = (size_t)N * K * sizeof(bf16);   // 32 MB

    const bool shape_ok = (M % BM2 == 0) && (N % BN2 == 0) && (K % 128 == 0) &&
                          (G % 8 == 0);

    if (shape_ok && ws_size >= xb_bytes + wt_bytes) {
        bf16* Xb = (bf16*)d_ws;
        bf16* Wt = (bf16*)((char*)d_ws + xb_bytes);
        const long n8 = (long)M * K / 8;
        convert_x_kernel<<<(int)((n8 + 255) / 256), 256, 0, stream>>>(x, Xb, n8);
        // waves = (K/64) * (N/8); threads = waves*64
        const long dq_threads = ((long)K >> 6) * (N / 8) * 64;
        dequant_wt64_kernel<<<(int)((dq_threads + 255) / 256), 256, 0, stream>>>(
            qw, scales, qzeros, Wt, N, K, G / 8);
        const int nbx = N / BN2;
        const int nwg = nbx * (M / BM2);       // 512
        gemm8_kernel<<<nwg, 512, 0, stream>>>(Xb, Wt, bias, out, M, N, K, nbx);
    } else {
        dim3 grid(N / BN, M / BM);
        gemm_fused_kernel<<<grid, 256, 0, stream>>>(
            x, qw, scales, qzeros, bias, out, M, N, K, G);
    }
}